// Round 2
// baseline (111.858 us; speedup 1.0000x reference)
//
#include <hip/hip_runtime.h>

// B=2, S=2048, D_MODEL=1024, H=16, E=64.  Inputs/outputs are FLOAT32.
// out = Q (norm * K^T V)  per (b,h)  -- reassociated, no S x S scores.
// Internally: projections via bf16 MFMA GEMM (X,W rounded to bf16),
// Q kept f32 in d_out, K/V bf16 in ws.

typedef __attribute__((ext_vector_type(8))) __bf16 bf16x8;
typedef __attribute__((ext_vector_type(8))) short short8;
typedef __attribute__((ext_vector_type(4))) float f32x4;

__device__ __forceinline__ float bf2f(unsigned short u) {
  union { unsigned int i; float f; } v; v.i = ((unsigned int)u) << 16; return v.f;
}
__device__ __forceinline__ unsigned short f2bf(float f) {
  union { float f; unsigned int i; } v; v.f = f;
  unsigned int u = v.i;
  u += 0x7fffu + ((u >> 16) & 1u);   // RNE
  return (unsigned short)(u >> 16);
}

// ---------------------------------------------------------------------------
// Kernel 1: C[r, c] = sum_d X[r,d] * W[c,d] + bias[c], R=4096, C=1024, K=1024
// 128x128 tile, BK=64, 4 waves (2x2 of 64x64), mfma_f32_16x16x32_bf16.
// f32 global -> regs -> bf16 -> LDS (T2 XOR-swizzled on 16B units).
// z=0: Q -> f32 d_out;  z=1: K -> bf16 ws;  z=2: V -> bf16 ws.
// ---------------------------------------------------------------------------
__global__ __launch_bounds__(256, 2) void proj_gemm(
    const float* __restrict__ X,
    const float* __restrict__ Wq,
    const float* __restrict__ Wk,
    const float* __restrict__ Wv,
    const float* __restrict__ Bq,
    const float* __restrict__ Bk,
    const float* __restrict__ Bv,
    float* __restrict__ Oq,
    unsigned short* __restrict__ Ok,
    unsigned short* __restrict__ Ov)
{
  __shared__ unsigned short smA[128 * 64];   // [row][k] bf16, 16 KB, swizzled
  __shared__ unsigned short smB[128 * 64];   // [col][k] bf16, 16 KB, swizzled

  const int tid = threadIdx.x;
  const int z = blockIdx.z;
  const float* __restrict__ W  = (z == 0) ? Wq : (z == 1) ? Wk : Wv;
  const float* __restrict__ Bb = (z == 0) ? Bq : (z == 1) ? Bk : Bv;

  const int rowBase = blockIdx.y * 128;
  const int colBase = blockIdx.x * 128;

  const int lane = tid & 63;
  const int wid  = tid >> 6;
  const int wr = (wid >> 1) * 64;
  const int wc = (wid & 1) * 64;
  const int lr = lane & 15;     // fragment row (A) / col (B,D)
  const int lk = lane >> 4;     // 0..3 k-subchunk / D row group

  f32x4 acc[4][4] = {};

  for (int kt = 0; kt < 16; ++kt) {
    const int k0 = kt * 64;
    // issue global loads early (overlap with previous compute)
    f32x4 ra[4][2], rb[4][2];
#pragma unroll
    for (int i = 0; i < 4; ++i) {
      const int si = i * 256 + tid;            // 0..1023
      const int row = si >> 3, seg = si & 7;
      const float* ga = X + (size_t)(rowBase + row) * 1024 + k0 + seg * 8;
      const float* gb = W + (size_t)(colBase + row) * 1024 + k0 + seg * 8;
      ra[i][0] = *(const f32x4*)ga;
      ra[i][1] = *(const f32x4*)(ga + 4);
      rb[i][0] = *(const f32x4*)gb;
      rb[i][1] = *(const f32x4*)(gb + 4);
    }
    __syncthreads();   // previous tile's compute done before overwrite
#pragma unroll
    for (int i = 0; i < 4; ++i) {
      const int si = i * 256 + tid;
      const int row = si >> 3, seg = si & 7;
      const int su = seg ^ (row & 7);          // T2 swizzle on 16B units
      union { short8 s; unsigned short u[8]; } pa, pb;
#pragma unroll
      for (int j = 0; j < 4; ++j) {
        pa.u[j]     = f2bf(ra[i][0][j]);
        pa.u[4 + j] = f2bf(ra[i][1][j]);
        pb.u[j]     = f2bf(rb[i][0][j]);
        pb.u[4 + j] = f2bf(rb[i][1][j]);
      }
      *(short8*)((char*)smA + row * 128 + su * 16) = pa.s;
      *(short8*)((char*)smB + row * 128 + su * 16) = pb.s;
    }
    __syncthreads();

#pragma unroll
    for (int ks = 0; ks < 2; ++ks) {
      bf16x8 av[4], bv4[4];
#pragma unroll
      for (int m = 0; m < 4; ++m) {
        const int row = wr + m * 16 + lr;
        const int u = (ks * 4 + lk) ^ (lr & 7);
        av[m] = *(const bf16x8*)((const char*)smA + row * 128 + u * 16);
      }
#pragma unroll
      for (int n = 0; n < 4; ++n) {
        const int col = wc + n * 16 + lr;
        const int u = (ks * 4 + lk) ^ (lr & 7);
        bv4[n] = *(const bf16x8*)((const char*)smB + col * 128 + u * 16);
      }
#pragma unroll
      for (int m = 0; m < 4; ++m)
#pragma unroll
        for (int n = 0; n < 4; ++n)
          acc[m][n] = __builtin_amdgcn_mfma_f32_16x16x32_bf16(av[m], bv4[n], acc[m][n], 0, 0, 0);
    }
    __syncthreads();
  }

  // epilogue: D mapping col = lane&15, row = (lane>>4)*4 + j (verified m89/m91)
  float bvals[4];
#pragma unroll
  for (int n = 0; n < 4; ++n)
    bvals[n] = Bb[colBase + wc + n * 16 + lr];
#pragma unroll
  for (int m = 0; m < 4; ++m) {
#pragma unroll
    for (int j = 0; j < 4; ++j) {
      const int row = rowBase + wr + m * 16 + lk * 4 + j;
#pragma unroll
      for (int n = 0; n < 4; ++n) {
        const int col = colBase + wc + n * 16 + lr;
        const float val = acc[m][n][j] + bvals[n];
        if (z == 0)      Oq[(size_t)row * 1024 + col] = val;
        else if (z == 1) Ok[(size_t)row * 1024 + col] = f2bf(val);
        else             Ov[(size_t)row * 1024 + col] = f2bf(val);
      }
    }
  }
}

// ---------------------------------------------------------------------------
// Kernel 2: partial M[f][e] = sum_{t in chunk} K[t,f] * V[t,e]  (f32)
// grid 256 = (b,h) x 8 S-chunks of 256.  K,V layout: [B,S,H*64] bf16.
// ---------------------------------------------------------------------------
__global__ __launch_bounds__(256) void kv_outer(
    const unsigned short* __restrict__ Kw,
    const unsigned short* __restrict__ Vw,
    float* __restrict__ Mpart)
{
  __shared__ float Ks[64 * 64];
  __shared__ float Vs[64 * 64];
  const int tid = threadIdx.x;
  const int blk = blockIdx.x;
  const int bh = blk >> 3, ch = blk & 7;
  const int b = bh >> 4, h = bh & 15;
  const int f0 = (tid & 15) * 4;
  const int e0 = (tid >> 4) * 4;
  float acc[4][4] = {};
  const int base = (b * 2048 + ch * 256) * 1024 + h * 64;

  for (int c = 0; c < 4; ++c) {
#pragma unroll
    for (int i = 0; i < 2; ++i) {
      const int si = i * 256 + tid;           // 0..511
      const int row = si >> 3, seg = si & 7;
      const int g = base + (c * 64 + row) * 1024 + seg * 8;
      short8 kr = *(const short8*)&Kw[g];
      short8 vr = *(const short8*)&Vw[g];
      f32x4 k0v, k1v, v0v, v1v;
#pragma unroll
      for (int j = 0; j < 4; ++j) {
        k0v[j] = bf2f((unsigned short)kr[j]);
        k1v[j] = bf2f((unsigned short)kr[4 + j]);
        v0v[j] = bf2f((unsigned short)vr[j]);
        v1v[j] = bf2f((unsigned short)vr[4 + j]);
      }
      *(f32x4*)&Ks[row * 64 + seg * 8]     = k0v;
      *(f32x4*)&Ks[row * 64 + seg * 8 + 4] = k1v;
      *(f32x4*)&Vs[row * 64 + seg * 8]     = v0v;
      *(f32x4*)&Vs[row * 64 + seg * 8 + 4] = v1v;
    }
    __syncthreads();
#pragma unroll 4
    for (int tt = 0; tt < 64; ++tt) {
      f32x4 kf = *(const f32x4*)&Ks[tt * 64 + f0];
      f32x4 vf = *(const f32x4*)&Vs[tt * 64 + e0];
#pragma unroll
      for (int i2 = 0; i2 < 4; ++i2)
#pragma unroll
        for (int j2 = 0; j2 < 4; ++j2)
          acc[i2][j2] += kf[i2] * vf[j2];
    }
    __syncthreads();
  }
  float* out = Mpart + blk * 4096;
#pragma unroll
  for (int i2 = 0; i2 < 4; ++i2) {
    f32x4 o = { acc[i2][0], acc[i2][1], acc[i2][2], acc[i2][3] };
    *(f32x4*)&out[(f0 + i2) * 64 + e0] = o;
  }
}

// ---------------------------------------------------------------------------
// Kernel 3: M[bh] = norm * sum_ch Mpart[bh][ch]   (32 blocks)
// ---------------------------------------------------------------------------
__global__ __launch_bounds__(256) void m_reduce(
    const float* __restrict__ Mpart, float* __restrict__ M)
{
  const int bh = blockIdx.x;
  const int tid = threadIdx.x;
#pragma unroll
  for (int i = 0; i < 4; ++i) {
    const int off = i * 1024 + tid * 4;
    f32x4 s = {};
#pragma unroll
    for (int ch = 0; ch < 8; ++ch)
      s += *(const f32x4*)&Mpart[(bh * 8 + ch) * 4096 + off];
    s *= 0.125f;   // 64^-0.5
    *(f32x4*)&M[bh * 4096 + off] = s;
  }
}

// ---------------------------------------------------------------------------
// Kernel 4: out[s, h*64+e] = sum_f Q[s, h*64+f] * M[bh][f][e]   (all f32)
// Q lives in d_out (written by kernel 1, f32); staged to LDS before overwrite.
// grid (16 s-chunks, 16 h, 2 b), 256 threads.
// ---------------------------------------------------------------------------
__global__ __launch_bounds__(256) void qm_out(
    float* __restrict__ QO, const float* __restrict__ M)
{
  __shared__ float Ms[64 * 64];     // 16 KB
  __shared__ float Qs[128 * 65];    // padded (65 words -> conflict-free rows)
  const int tid = threadIdx.x;
  const int b = blockIdx.z, h = blockIdx.y, s0 = blockIdx.x * 128;
  const int bh = b * 16 + h;

#pragma unroll
  for (int i = 0; i < 4; ++i) {
    const int off = i * 1024 + tid * 4;
    *(f32x4*)&Ms[off] = *(const f32x4*)&M[bh * 4096 + off];
  }
  const size_t rowbase = ((size_t)b * 2048 + s0) * 1024 + h * 64;
#pragma unroll
  for (int i = 0; i < 8; ++i) {
    const int slot = i * 256 + tid;          // 0..2047 float4 slots
    const int row = slot >> 4, c4 = slot & 15;
    f32x4 q = *(const f32x4*)&QO[rowbase + (size_t)row * 1024 + c4 * 4];
#pragma unroll
    for (int j = 0; j < 4; ++j)
      Qs[row * 65 + c4 * 4 + j] = q[j];
  }
  __syncthreads();

  const int s = (tid >> 3) * 4;       // 4 rows
  const int e0 = (tid & 7) * 8;       // 8 cols
  float acc[4][8] = {};
  for (int f = 0; f < 64; ++f) {
    f32x4 m0 = *(const f32x4*)&Ms[f * 64 + e0];
    f32x4 m1 = *(const f32x4*)&Ms[f * 64 + e0 + 4];
#pragma unroll
    for (int i = 0; i < 4; ++i) {
      const float q = Qs[(s + i) * 65 + f];
#pragma unroll
      for (int j = 0; j < 4; ++j) {
        acc[i][j]     += q * m0[j];
        acc[i][j + 4] += q * m1[j];
      }
    }
  }
#pragma unroll
  for (int i = 0; i < 4; ++i) {
    f32x4 o0 = { acc[i][0], acc[i][1], acc[i][2], acc[i][3] };
    f32x4 o1 = { acc[i][4], acc[i][5], acc[i][6], acc[i][7] };
    *(f32x4*)&QO[rowbase + (size_t)(s + i) * 1024 + e0]     = o0;
    *(f32x4*)&QO[rowbase + (size_t)(s + i) * 1024 + e0 + 4] = o1;
  }
}

extern "C" void kernel_launch(void* const* d_in, const int* in_sizes, int n_in,
                              void* d_out, int out_size, void* d_ws, size_t ws_size,
                              hipStream_t stream) {
  const float* x  = (const float*)d_in[0];
  const float* Wq = (const float*)d_in[1];
  const float* Wk = (const float*)d_in[2];
  const float* Wv = (const float*)d_in[3];
  const float* bq = (const float*)d_in[4];
  const float* bk = (const float*)d_in[5];
  const float* bv = (const float*)d_in[6];
  float* out = (float*)d_out;

  char* ws = (char*)d_ws;
  unsigned short* Kws   = (unsigned short*)(ws);                       // 8 MiB
  unsigned short* Vws   = (unsigned short*)(ws + 8ull * 1024 * 1024);  // 8 MiB
  float*          Mpart = (float*)(ws + 16ull * 1024 * 1024);          // 4 MiB
  float*          Mfin  = (float*)(ws + 20ull * 1024 * 1024);          // 0.5 MiB

  dim3 g1(8, 32, 3);   // col-tiles, row-tiles, {Q,K,V}
  proj_gemm<<<g1, 256, 0, stream>>>(x, Wq, Wk, Wv, bq, bk, bv, out, Kws, Vws);
  kv_outer<<<256, 256, 0, stream>>>(Kws, Vws, Mpart);
  m_reduce<<<32, 256, 0, stream>>>(Mpart, Mfin);
  qm_out<<<dim3(16, 16, 2), 256, 0, stream>>>(out, Mfin);
}

// Round 3
// 70.769 us; speedup vs baseline: 1.5806x; 1.5806x over previous
//
#include <hip/hip_runtime.h>

// B=2, S=2048, D_MODEL=1024, H=16, E=64.  Inputs/outputs FLOAT32.
// out = Q (norm * K^T V)  -- reassociated, no S x S scores.
// Pipeline: convert_pack (f32->bf16 X, Wcat, Bcat) -> qkv_gemm (MFMA, one
// fused [4096,3072] GEMM, global_load_lds w16, T2 swizzle via pre-swizzled
// source) -> kv_outer -> m_reduce -> qm_out.

typedef __attribute__((ext_vector_type(8))) __bf16 bf16x8;
typedef __attribute__((ext_vector_type(8))) short short8;
typedef __attribute__((ext_vector_type(4))) float f32x4;

#define NX  4194304   // 4096*1024
#define NW1 1048576   // 1024*1024
#define NW  3145728   // 3*NW1

__device__ __forceinline__ float bf2f(unsigned short u) {
  union { unsigned int i; float f; } v; v.i = ((unsigned int)u) << 16; return v.f;
}
__device__ __forceinline__ unsigned short f2bf(float f) {
  union { float f; unsigned int i; } v; v.f = f;
  unsigned int u = v.i;
  u += 0x7fffu + ((u >> 16) & 1u);   // RNE
  return (unsigned short)(u >> 16);
}

__device__ __forceinline__ void gload_lds16(const void* g, void* l) {
  __builtin_amdgcn_global_load_lds(
      (const __attribute__((address_space(1))) void*)(unsigned long long)(g),
      (__attribute__((address_space(3))) void*)(unsigned int)(unsigned long long)(l),
      16, 0, 0);
}

// ---------------------------------------------------------------------------
// Kernel 0: f32 -> bf16 convert/pack.  Xbf[4096][1024], Wcat[3072][1024]
// (rows 0-1023 Wq, 1024-2047 Wk, 2048-3071 Wv), Bcat[3072] f32.
// 8 elems/thread.
// ---------------------------------------------------------------------------
__global__ __launch_bounds__(256) void convert_pack(
    const float* __restrict__ x,
    const float* __restrict__ wq, const float* __restrict__ wk,
    const float* __restrict__ wv,
    const float* __restrict__ bq, const float* __restrict__ bk,
    const float* __restrict__ bv,
    unsigned short* __restrict__ Xbf, unsigned short* __restrict__ Wcat,
    float* __restrict__ Bcat)
{
  const long long t8 = ((long long)blockIdx.x * 256 + threadIdx.x) * 8;
  const float* src;
  unsigned short* dst;
  long long off;
  if (t8 < NX) {
    src = x; dst = Xbf; off = t8;
  } else if (t8 < NX + NW) {
    const long long w = t8 - NX;
    const int z = (int)(w >> 20);
    off = w & (NW1 - 1);
    src = (z == 0) ? wq : (z == 1) ? wk : wv;
    dst = Wcat + (long long)z * NW1;
  } else if (t8 < NX + NW + 3072) {
    const long long bo = t8 - (NX + NW);
    const int z = (int)(bo >> 10);
    const long long o2 = bo & 1023;
    const float* bsrc = (z == 0) ? bq : (z == 1) ? bk : bv;
    *(f32x4*)(Bcat + z * 1024 + o2)     = *(const f32x4*)(bsrc + o2);
    *(f32x4*)(Bcat + z * 1024 + o2 + 4) = *(const f32x4*)(bsrc + o2 + 4);
    return;
  } else {
    return;
  }
  f32x4 v0 = *(const f32x4*)(src + off);
  f32x4 v1 = *(const f32x4*)(src + off + 4);
  union { short8 s; unsigned short u[8]; } o;
#pragma unroll
  for (int j = 0; j < 4; ++j) {
    o.u[j]     = f2bf(v0[j]);
    o.u[4 + j] = f2bf(v1[j]);
  }
  *(short8*)(dst + off) = o.s;
}

// ---------------------------------------------------------------------------
// Kernel 1: QKV[r, c] = sum_d Xbf[r,d]*Wcat[c,d] + Bcat[c], bf16 out.
// R=4096, C=3072, K=1024.  128x128 tile, BK=64, 4 waves (2x2 of 64x64),
// mfma_f32_16x16x32_bf16, global_load_lds w16, T2 swizzle on 16B units
// (linear LDS dest + pre-swizzled global src + swizzled ds_read).
// Grid 768 (24 col x 32 row), bijective XCD swizzle (768 % 8 == 0).
// ---------------------------------------------------------------------------
__global__ __launch_bounds__(256, 2) void qkv_gemm(
    const unsigned short* __restrict__ Xbf,
    const unsigned short* __restrict__ Wcat,
    const float* __restrict__ Bcat,
    unsigned short* __restrict__ QKV)
{
  __shared__ unsigned short smA[128 * 64];   // 16 KB
  __shared__ unsigned short smB[128 * 64];   // 16 KB

  const int tid = threadIdx.x;
  int bid = blockIdx.x;
  bid = (bid & 7) * 96 + (bid >> 3);         // XCD-contiguous chunks
  const int colBase = (bid % 24) * 128;
  const int rowBase = (bid / 24) * 128;

  const int lane = tid & 63;
  const int wid  = tid >> 6;
  const int wr = (wid >> 1) * 64;
  const int wc = (wid & 1) * 64;
  const int lr = lane & 15;
  const int lk = lane >> 4;

  f32x4 acc[4][4] = {};

  for (int kt = 0; kt < 16; ++kt) {
    const int k0 = kt * 64;
#pragma unroll
    for (int i = 0; i < 4; ++i) {
      const int si = i * 256 + tid;          // 0..1023
      const int row = si >> 3, seg = si & 7;
      const int sseg = seg ^ (row & 7);      // inverse-swizzled source
      gload_lds16(Xbf  + (size_t)(rowBase + row) * 1024 + k0 + sseg * 8,
                  smA + (si & ~63) * 8);
      gload_lds16(Wcat + (size_t)(colBase + row) * 1024 + k0 + sseg * 8,
                  smB + (si & ~63) * 8);
    }
    __syncthreads();                         // drains vmcnt before barrier

#pragma unroll
    for (int ks = 0; ks < 2; ++ks) {
      bf16x8 av[4], bv4[4];
#pragma unroll
      for (int m = 0; m < 4; ++m) {
        const int row = wr + m * 16 + lr;
        av[m] = *(const bf16x8*)((const char*)smA + row * 128 +
                                 (((ks * 4 + lk) ^ (row & 7)) * 16));
      }
#pragma unroll
      for (int n = 0; n < 4; ++n) {
        const int row = wc + n * 16 + lr;
        bv4[n] = *(const bf16x8*)((const char*)smB + row * 128 +
                                  (((ks * 4 + lk) ^ (row & 7)) * 16));
      }
#pragma unroll
      for (int m = 0; m < 4; ++m)
#pragma unroll
        for (int n = 0; n < 4; ++n)
          acc[m][n] = __builtin_amdgcn_mfma_f32_16x16x32_bf16(av[m], bv4[n], acc[m][n], 0, 0, 0);
    }
    __syncthreads();
  }

  // D mapping: col = lane&15, row = (lane>>4)*4 + j
  float bvals[4];
#pragma unroll
  for (int n = 0; n < 4; ++n)
    bvals[n] = Bcat[colBase + wc + n * 16 + lr];
#pragma unroll
  for (int m = 0; m < 4; ++m) {
#pragma unroll
    for (int j = 0; j < 4; ++j) {
      const int row = rowBase + wr + m * 16 + lk * 4 + j;
#pragma unroll
      for (int n = 0; n < 4; ++n) {
        const int col = colBase + wc + n * 16 + lr;
        QKV[(size_t)row * 3072 + col] = f2bf(acc[m][n][j] + bvals[n]);
      }
    }
  }
}

// ---------------------------------------------------------------------------
// Kernel 2: partial M[f][e] = sum_{t in chunk} K[t,f]*V[t,e]  (f32)
// grid 256 = (b,h) x 8 S-chunks of 256.  K at QKV col 1024+h*64, V at 2048+.
// ---------------------------------------------------------------------------
__global__ __launch_bounds__(256) void kv_outer(
    const unsigned short* __restrict__ QKV, float* __restrict__ Mpart)
{
  __shared__ float Ks[64 * 64];
  __shared__ float Vs[64 * 64];
  const int tid = threadIdx.x;
  const int blk = blockIdx.x;
  const int bh = blk >> 3, ch = blk & 7;
  const int b = bh >> 4, h = bh & 15;
  const int f0 = (tid & 15) * 4;
  const int e0 = (tid >> 4) * 4;
  float acc[4][4] = {};
  const size_t base = ((size_t)b * 2048 + ch * 256) * 3072 + h * 64;

  for (int c = 0; c < 4; ++c) {
#pragma unroll
    for (int i = 0; i < 2; ++i) {
      const int si = i * 256 + tid;          // 0..511
      const int row = si >> 3, seg = si & 7;
      const size_t g = base + (size_t)(c * 64 + row) * 3072 + seg * 8;
      short8 kr = *(const short8*)&QKV[g + 1024];
      short8 vr = *(const short8*)&QKV[g + 2048];
      f32x4 k0v, k1v, v0v, v1v;
#pragma unroll
      for (int j = 0; j < 4; ++j) {
        k0v[j] = bf2f((unsigned short)kr[j]);
        k1v[j] = bf2f((unsigned short)kr[4 + j]);
        v0v[j] = bf2f((unsigned short)vr[j]);
        v1v[j] = bf2f((unsigned short)vr[4 + j]);
      }
      *(f32x4*)&Ks[row * 64 + seg * 8]     = k0v;
      *(f32x4*)&Ks[row * 64 + seg * 8 + 4] = k1v;
      *(f32x4*)&Vs[row * 64 + seg * 8]     = v0v;
      *(f32x4*)&Vs[row * 64 + seg * 8 + 4] = v1v;
    }
    __syncthreads();
#pragma unroll 4
    for (int tt = 0; tt < 64; ++tt) {
      f32x4 kf = *(const f32x4*)&Ks[tt * 64 + f0];
      f32x4 vf = *(const f32x4*)&Vs[tt * 64 + e0];
#pragma unroll
      for (int i2 = 0; i2 < 4; ++i2)
#pragma unroll
        for (int j2 = 0; j2 < 4; ++j2)
          acc[i2][j2] += kf[i2] * vf[j2];
    }
    __syncthreads();
  }
  float* out = Mpart + (size_t)blk * 4096;
#pragma unroll
  for (int i2 = 0; i2 < 4; ++i2) {
    f32x4 o = { acc[i2][0], acc[i2][1], acc[i2][2], acc[i2][3] };
    *(f32x4*)&out[(f0 + i2) * 64 + e0] = o;
  }
}

// ---------------------------------------------------------------------------
// Kernel 3: M[bh] = norm * sum_ch Mpart[bh][ch]   (32 blocks)
// ---------------------------------------------------------------------------
__global__ __launch_bounds__(256) void m_reduce(
    const float* __restrict__ Mpart, float* __restrict__ M)
{
  const int bh = blockIdx.x;
  const int tid = threadIdx.x;
#pragma unroll
  for (int i = 0; i < 4; ++i) {
    const int off = i * 1024 + tid * 4;
    f32x4 s = {};
#pragma unroll
    for (int ch = 0; ch < 8; ++ch)
      s += *(const f32x4*)&Mpart[((size_t)bh * 8 + ch) * 4096 + off];
    s *= 0.125f;   // 64^-0.5
    *(f32x4*)&M[(size_t)bh * 4096 + off] = s;
  }
}

// ---------------------------------------------------------------------------
// Kernel 4: Out[s, h*64+e] = sum_f Q[s,f] * M[bh][f][e]; Q bf16 from QKV,
// Out f32 = d_out.  grid (16 s-chunks of 128, 16 h, 2 b), 256 threads.
// ---------------------------------------------------------------------------
__global__ __launch_bounds__(256) void qm_out(
    const unsigned short* __restrict__ QKV, const float* __restrict__ M,
    float* __restrict__ Out)
{
  __shared__ float Ms[64 * 64];     // 16 KB
  __shared__ float Qs[128 * 65];    // padded rows
  const int tid = threadIdx.x;
  const int b = blockIdx.z, h = blockIdx.y, s0 = blockIdx.x * 128;
  const int bh = b * 16 + h;

#pragma unroll
  for (int i = 0; i < 4; ++i) {
    const int off = i * 1024 + tid * 4;
    *(f32x4*)&Ms[off] = *(const f32x4*)&M[(size_t)bh * 4096 + off];
  }
  const size_t qbase = ((size_t)b * 2048 + s0) * 3072 + h * 64;
#pragma unroll
  for (int i = 0; i < 4; ++i) {
    const int si = i * 256 + tid;            // 0..1023
    const int row = si >> 3, seg = si & 7;
    short8 q = *(const short8*)&QKV[qbase + (size_t)row * 3072 + seg * 8];
#pragma unroll
    for (int j = 0; j < 8; ++j)
      Qs[row * 65 + seg * 8 + j] = bf2f((unsigned short)q[j]);
  }
  __syncthreads();

  const int s = (tid >> 3) * 4;       // 4 rows / thread
  const int e0 = (tid & 7) * 8;       // 8 cols / thread
  float acc2[4][8] = {};
  for (int f = 0; f < 64; ++f) {
    f32x4 m0 = *(const f32x4*)&Ms[f * 64 + e0];
    f32x4 m1 = *(const f32x4*)&Ms[f * 64 + e0 + 4];
#pragma unroll
    for (int i = 0; i < 4; ++i) {
      const float q = Qs[(s + i) * 65 + f];
#pragma unroll
      for (int j = 0; j < 4; ++j) {
        acc2[i][j]     += q * m0[j];
        acc2[i][j + 4] += q * m1[j];
      }
    }
  }
  const size_t obase = ((size_t)b * 2048 + s0) * 1024 + h * 64;
#pragma unroll
  for (int i = 0; i < 4; ++i) {
    f32x4 o0 = { acc2[i][0], acc2[i][1], acc2[i][2], acc2[i][3] };
    f32x4 o1 = { acc2[i][4], acc2[i][5], acc2[i][6], acc2[i][7] };
    *(f32x4*)&Out[obase + (size_t)(s + i) * 1024 + e0]     = o0;
    *(f32x4*)&Out[obase + (size_t)(s + i) * 1024 + e0 + 4] = o1;
  }
}

extern "C" void kernel_launch(void* const* d_in, const int* in_sizes, int n_in,
                              void* d_out, int out_size, void* d_ws, size_t ws_size,
                              hipStream_t stream) {
  const float* x  = (const float*)d_in[0];
  const float* Wq = (const float*)d_in[1];
  const float* Wk = (const float*)d_in[2];
  const float* Wv = (const float*)d_in[3];
  const float* bq = (const float*)d_in[4];
  const float* bk = (const float*)d_in[5];
  const float* bv = (const float*)d_in[6];
  float* out = (float*)d_out;

  char* ws = (char*)d_ws;
  const size_t MiB = 1024ull * 1024ull;
  unsigned short* Xbf   = (unsigned short*)(ws);              //  8 MiB
  unsigned short* Wcat  = (unsigned short*)(ws + 8  * MiB);   //  6 MiB
  float*          Bcat  = (float*)         (ws + 14 * MiB);   // 12 KiB
  unsigned short* QKV   = (unsigned short*)(ws + 15 * MiB);   // 24 MiB
  float*          Mpart = (float*)         (ws + 39 * MiB);   //  4 MiB
  float*          Mfin  = (float*)         (ws + 43 * MiB);   // 512 KiB

  // (NX + NW + 3072)/8 = 917888 threads -> 3586 blocks
  convert_pack<<<3586, 256, 0, stream>>>(x, Wq, Wk, Wv, bq, bk, bv,
                                         Xbf, Wcat, Bcat);
  qkv_gemm<<<768, 256, 0, stream>>>(Xbf, Wcat, Bcat, QKV);
  kv_outer<<<256, 256, 0, stream>>>(QKV, Mpart);
  m_reduce<<<32, 256, 0, stream>>>(Mpart, Mfin);
  qm_out<<<dim3(16, 16, 2), 256, 0, stream>>>(QKV, Mfin, out);
}

// Round 4
// 65.362 us; speedup vs baseline: 1.7113x; 1.0827x over previous
//
#include <hip/hip_runtime.h>

// B=2, S=2048, D_MODEL=1024, H=16, E=64.  Inputs/outputs FLOAT32.
// out = Q (norm * K^T V)  -- reassociated, no S x S scores.
// Pipeline: convert_pack (f32->bf16) -> qkv_gemm (MFMA, fused [4096,3072],
// global_load_lds w16, T2 swizzle, TRANSPOSED per-head epilogue stores
// Qt/Kt/Vt[bh][64][2048]) -> kv_outer (MFMA) -> m_reduce -> qm_out.

typedef __attribute__((ext_vector_type(8))) __bf16 bf16x8;
typedef __attribute__((ext_vector_type(8))) short short8;
typedef __attribute__((ext_vector_type(4))) float f32x4;
typedef __attribute__((ext_vector_type(4))) unsigned short ushort4v;

#define NX  4194304   // 4096*1024
#define NW1 1048576   // 1024*1024
#define NW  3145728   // 3*NW1

__device__ __forceinline__ float bf2f(unsigned short u) {
  union { unsigned int i; float f; } v; v.i = ((unsigned int)u) << 16; return v.f;
}
__device__ __forceinline__ unsigned short f2bf(float f) {
  union { float f; unsigned int i; } v; v.f = f;
  unsigned int u = v.i;
  u += 0x7fffu + ((u >> 16) & 1u);   // RNE
  return (unsigned short)(u >> 16);
}

__device__ __forceinline__ void gload_lds16(const void* g, void* l) {
  __builtin_amdgcn_global_load_lds(
      (const __attribute__((address_space(1))) void*)(unsigned long long)(g),
      (__attribute__((address_space(3))) void*)(unsigned int)(unsigned long long)(l),
      16, 0, 0);
}

// ---------------------------------------------------------------------------
// Kernel 0: f32 -> bf16 convert/pack.  Xbf[4096][1024], Wcat[3072][1024],
// Bcat[3072] f32.
// ---------------------------------------------------------------------------
__global__ __launch_bounds__(256) void convert_pack(
    const float* __restrict__ x,
    const float* __restrict__ wq, const float* __restrict__ wk,
    const float* __restrict__ wv,
    const float* __restrict__ bq, const float* __restrict__ bk,
    const float* __restrict__ bv,
    unsigned short* __restrict__ Xbf, unsigned short* __restrict__ Wcat,
    float* __restrict__ Bcat)
{
  const long long t8 = ((long long)blockIdx.x * 256 + threadIdx.x) * 8;
  const float* src;
  unsigned short* dst;
  long long off;
  if (t8 < NX) {
    src = x; dst = Xbf; off = t8;
  } else if (t8 < NX + NW) {
    const long long w = t8 - NX;
    const int z = (int)(w >> 20);
    off = w & (NW1 - 1);
    src = (z == 0) ? wq : (z == 1) ? wk : wv;
    dst = Wcat + (long long)z * NW1;
  } else if (t8 < NX + NW + 3072) {
    const long long bo = t8 - (NX + NW);
    const int z = (int)(bo >> 10);
    const long long o2 = bo & 1023;
    const float* bsrc = (z == 0) ? bq : (z == 1) ? bk : bv;
    *(f32x4*)(Bcat + z * 1024 + o2)     = *(const f32x4*)(bsrc + o2);
    *(f32x4*)(Bcat + z * 1024 + o2 + 4) = *(const f32x4*)(bsrc + o2 + 4);
    return;
  } else {
    return;
  }
  f32x4 v0 = *(const f32x4*)(src + off);
  f32x4 v1 = *(const f32x4*)(src + off + 4);
  union { short8 s; unsigned short u[8]; } o;
#pragma unroll
  for (int j = 0; j < 4; ++j) {
    o.u[j]     = f2bf(v0[j]);
    o.u[4 + j] = f2bf(v1[j]);
  }
  *(short8*)(dst + off) = o.s;
}

// ---------------------------------------------------------------------------
// Kernel 1: C[r, c] = sum_d Xbf[r,d]*Wcat[c,d] + Bcat[c].
// R=4096, C=3072, K=1024.  128x128 tile, BK=64, 4 waves (2x2 of 64x64),
// mfma_f32_16x16x32_bf16, global_load_lds w16, T2 swizzle (pre-swizzled src).
// Epilogue: per-head TRANSPOSED bf16 stores -> Qt/Kt/Vt[bh][64][2048],
// 8B packed (4 consecutive t per store).  Grid 768, bijective XCD swizzle.
// ---------------------------------------------------------------------------
__global__ __launch_bounds__(256, 2) void qkv_gemm(
    const unsigned short* __restrict__ Xbf,
    const unsigned short* __restrict__ Wcat,
    const float* __restrict__ Bcat,
    unsigned short* __restrict__ Qt,
    unsigned short* __restrict__ Kt,
    unsigned short* __restrict__ Vt)
{
  __shared__ unsigned short smA[128 * 64];   // 16 KB
  __shared__ unsigned short smB[128 * 64];   // 16 KB

  const int tid = threadIdx.x;
  int bid = blockIdx.x;
  bid = (bid & 7) * 96 + (bid >> 3);         // XCD-contiguous chunks
  const int colBase = (bid % 24) * 128;
  const int rowBase = (bid / 24) * 128;

  const int lane = tid & 63;
  const int wid  = tid >> 6;
  const int wr = (wid >> 1) * 64;
  const int wc = (wid & 1) * 64;
  const int lr = lane & 15;
  const int lk = lane >> 4;

  f32x4 acc[4][4] = {};

  for (int kt = 0; kt < 16; ++kt) {
    const int k0 = kt * 64;
#pragma unroll
    for (int i = 0; i < 4; ++i) {
      const int si = i * 256 + tid;          // 0..1023
      const int row = si >> 3, seg = si & 7;
      const int sseg = seg ^ (row & 7);      // inverse-swizzled source
      gload_lds16(Xbf  + (size_t)(rowBase + row) * 1024 + k0 + sseg * 8,
                  smA + (si & ~63) * 8);
      gload_lds16(Wcat + (size_t)(colBase + row) * 1024 + k0 + sseg * 8,
                  smB + (si & ~63) * 8);
    }
    __syncthreads();                         // drains vmcnt before barrier

#pragma unroll
    for (int ks = 0; ks < 2; ++ks) {
      bf16x8 av[4], bv4[4];
#pragma unroll
      for (int m = 0; m < 4; ++m) {
        const int row = wr + m * 16 + lr;
        av[m] = *(const bf16x8*)((const char*)smA + row * 128 +
                                 (((ks * 4 + lk) ^ (row & 7)) * 16));
      }
#pragma unroll
      for (int n = 0; n < 4; ++n) {
        const int row = wc + n * 16 + lr;
        bv4[n] = *(const bf16x8*)((const char*)smB + row * 128 +
                                  (((ks * 4 + lk) ^ (row & 7)) * 16));
      }
#pragma unroll
      for (int m = 0; m < 4; ++m)
#pragma unroll
        for (int n = 0; n < 4; ++n)
          acc[m][n] = __builtin_amdgcn_mfma_f32_16x16x32_bf16(av[m], bv4[n], acc[m][n], 0, 0, 0);
    }
    __syncthreads();
  }

  // Epilogue.  D mapping: col = lane&15, row = (lane>>4)*4 + j.
  // zone uniform per block (colBase is 128-aligned, zones at 1024).
  const int zone = colBase >> 10;
  unsigned short* __restrict__ T = (zone == 0) ? Qt : (zone == 1) ? Kt : Vt;
  const int bB = rowBase >> 11;              // batch (block spans one batch)
#pragma unroll
  for (int n = 0; n < 4; ++n) {
    const int colG = colBase + wc + n * 16 + lr;
    const float bval = Bcat[colG];
    const int hf = (colG >> 6) & 15;
    const int f  = colG & 63;
    const size_t rowOff = ((size_t)(bB * 16 + hf) * 64 + f) * 2048;
#pragma unroll
    for (int m = 0; m < 4; ++m) {
      const int t = (rowBase + wr + m * 16 + lk * 4) & 2047;
      ushort4v pk;
#pragma unroll
      for (int j = 0; j < 4; ++j)
        pk[j] = f2bf(acc[m][n][j] + bval);
      *(ushort4v*)&T[rowOff + t] = pk;
    }
  }
}

// ---------------------------------------------------------------------------
// Kernel 2 (MFMA): Mpart[blk][f][e] = sum_{t in chunk} Kt[bh][f][t]*Vt[bh][e][t]
// grid 256 blocks x 64 threads (1 wave).  blk = bh*8 + tchunk.
// ---------------------------------------------------------------------------
__global__ __launch_bounds__(64) void kv_outer(
    const unsigned short* __restrict__ Kt,
    const unsigned short* __restrict__ Vt,
    float* __restrict__ Mpart)
{
  const int lane = threadIdx.x;
  const int blk = blockIdx.x;
  const int bh = blk >> 3, tc = blk & 7;
  const int lr = lane & 15, lk = lane >> 4;
  const size_t base = (size_t)bh * 64 * 2048;

  f32x4 acc[4][4] = {};
#pragma unroll
  for (int ks = 0; ks < 8; ++ks) {
    const int t0 = tc * 256 + ks * 32 + lk * 8;
    bf16x8 af[4], bf[4];
#pragma unroll
    for (int m = 0; m < 4; ++m)
      af[m] = *(const bf16x8*)&Kt[base + (size_t)(m * 16 + lr) * 2048 + t0];
#pragma unroll
    for (int n = 0; n < 4; ++n)
      bf[n] = *(const bf16x8*)&Vt[base + (size_t)(n * 16 + lr) * 2048 + t0];
#pragma unroll
    for (int m = 0; m < 4; ++m)
#pragma unroll
      for (int n = 0; n < 4; ++n)
        acc[m][n] = __builtin_amdgcn_mfma_f32_16x16x32_bf16(af[m], bf[n], acc[m][n], 0, 0, 0);
  }
  float* out = Mpart + (size_t)blk * 4096;
#pragma unroll
  for (int m = 0; m < 4; ++m)
#pragma unroll
    for (int n = 0; n < 4; ++n)
#pragma unroll
      for (int j = 0; j < 4; ++j)
        out[(m * 16 + lk * 4 + j) * 64 + n * 16 + lr] = acc[m][n][j];
}

// ---------------------------------------------------------------------------
// Kernel 3: M[bh] = norm * sum_ch Mpart[bh*8+ch]   (32 blocks)
// ---------------------------------------------------------------------------
__global__ __launch_bounds__(256) void m_reduce(
    const float* __restrict__ Mpart, float* __restrict__ M)
{
  const int bh = blockIdx.x;
  const int tid = threadIdx.x;
#pragma unroll
  for (int i = 0; i < 4; ++i) {
    const int off = i * 1024 + tid * 4;
    f32x4 s = {};
#pragma unroll
    for (int ch = 0; ch < 8; ++ch)
      s += *(const f32x4*)&Mpart[((size_t)bh * 8 + ch) * 4096 + off];
    s *= 0.125f;   // 64^-0.5
    *(f32x4*)&M[(size_t)bh * 4096 + off] = s;
  }
}

// ---------------------------------------------------------------------------
// Kernel 4: Out[s, h*64+e] = sum_f Qt[bh][f][s] * M[bh][f][e]   (f32 out)
// grid (16 s-chunks of 128, 16 h, 2 b), 256 threads.
// ---------------------------------------------------------------------------
__global__ __launch_bounds__(256) void qm_out(
    const unsigned short* __restrict__ Qt, const float* __restrict__ M,
    float* __restrict__ Out)
{
  __shared__ float Ms[64 * 64];      // 16 KB
  __shared__ float Qst[64 * 132];    // [f][s] padded, ~33 KB
  const int tid = threadIdx.x;
  const int b = blockIdx.z, h = blockIdx.y, s0 = blockIdx.x * 128;
  const int bh = b * 16 + h;

#pragma unroll
  for (int i = 0; i < 4; ++i) {
    const int off = i * 1024 + tid * 4;
    *(f32x4*)&Ms[off] = *(const f32x4*)&M[(size_t)bh * 4096 + off];
  }
  const size_t qbase = (size_t)bh * 64 * 2048;
#pragma unroll
  for (int i = 0; i < 4; ++i) {
    const int slot = i * 256 + tid;          // 0..1023
    const int f = slot >> 4, c = slot & 15;  // 16 chunks of 8 per f-row
    short8 q = *(const short8*)&Qt[qbase + (size_t)f * 2048 + s0 + c * 8];
#pragma unroll
    for (int j = 0; j < 8; ++j)
      Qst[f * 132 + c * 8 + j] = bf2f((unsigned short)q[j]);
  }
  __syncthreads();

  const int s = (tid >> 3) * 4;       // 4 rows / thread
  const int e0 = (tid & 7) * 8;       // 8 cols / thread
  float acc2[4][8] = {};
  for (int f = 0; f < 64; ++f) {
    f32x4 m0 = *(const f32x4*)&Ms[f * 64 + e0];
    f32x4 m1 = *(const f32x4*)&Ms[f * 64 + e0 + 4];
#pragma unroll
    for (int i = 0; i < 4; ++i) {
      const float q = Qst[f * 132 + s + i];
#pragma unroll
      for (int j = 0; j < 4; ++j) {
        acc2[i][j]     += q * m0[j];
        acc2[i][j + 4] += q * m1[j];
      }
    }
  }
  const size_t obase = ((size_t)b * 2048 + s0) * 1024 + h * 64;
#pragma unroll
  for (int i = 0; i < 4; ++i) {
    f32x4 o0 = { acc2[i][0], acc2[i][1], acc2[i][2], acc2[i][3] };
    f32x4 o1 = { acc2[i][4], acc2[i][5], acc2[i][6], acc2[i][7] };
    *(f32x4*)&Out[obase + (size_t)(s + i) * 1024 + e0]     = o0;
    *(f32x4*)&Out[obase + (size_t)(s + i) * 1024 + e0 + 4] = o1;
  }
}

extern "C" void kernel_launch(void* const* d_in, const int* in_sizes, int n_in,
                              void* d_out, int out_size, void* d_ws, size_t ws_size,
                              hipStream_t stream) {
  const float* x  = (const float*)d_in[0];
  const float* Wq = (const float*)d_in[1];
  const float* Wk = (const float*)d_in[2];
  const float* Wv = (const float*)d_in[3];
  const float* bq = (const float*)d_in[4];
  const float* bk = (const float*)d_in[5];
  const float* bv = (const float*)d_in[6];
  float* out = (float*)d_out;

  char* ws = (char*)d_ws;
  const size_t MiB = 1024ull * 1024ull;
  unsigned short* Xbf   = (unsigned short*)(ws);              //  8 MiB
  unsigned short* Wcat  = (unsigned short*)(ws + 8  * MiB);   //  6 MiB
  float*          Bcat  = (float*)         (ws + 14 * MiB);   // 12 KiB
  unsigned short* Qt    = (unsigned short*)(ws + 15 * MiB);   //  8 MiB
  unsigned short* Kt    = (unsigned short*)(ws + 23 * MiB);   //  8 MiB
  unsigned short* Vt    = (unsigned short*)(ws + 31 * MiB);   //  8 MiB
  float*          Mpart = (float*)         (ws + 39 * MiB);   //  4 MiB
  float*          Mfin  = (float*)         (ws + 43 * MiB);   // 512 KiB

  convert_pack<<<3586, 256, 0, stream>>>(x, Wq, Wk, Wv, bq, bk, bv,
                                         Xbf, Wcat, Bcat);
  qkv_gemm<<<768, 256, 0, stream>>>(Xbf, Wcat, Bcat, Qt, Kt, Vt);
  kv_outer<<<256, 64, 0, stream>>>(Kt, Vt, Mpart);
  m_reduce<<<32, 256, 0, stream>>>(Mpart, Mfin);
  qm_out<<<dim3(16, 16, 2), 256, 0, stream>>>(Qt, Mfin, out);
}